// Round 4
// baseline (567.348 us; speedup 1.0000x reference)
//
#include <hip/hip_runtime.h>
#include <hip/hip_bf16.h>

// Problem constants
#define Tt   50
#define Dd   64
#define NOUT 100
#define G4   512   // 4*H
#define K0S  72    // a0 LDS stride (64 x-cols + 8 pad)
#define K1P  264   // a1 LDS stride (256 + 8 pad)
#define BM   16    // batch rows per workgroup (grid 256 = 4096/16)

typedef __attribute__((ext_vector_type(8))) short  short8;
typedef __attribute__((ext_vector_type(4))) float  floatx4;

#if __has_builtin(__builtin_amdgcn_exp2f)
#define EXP2(v) __builtin_amdgcn_exp2f(v)
#else
#define EXP2(v) exp2f(v)
#endif
__device__ __forceinline__ float rcp_(float v) { return __builtin_amdgcn_rcpf(v); }
#define KN2L2E (-2.8853900817779268f)   // -2*log2(e), for tanh(c) with natural-units c

// LDS-only barrier: publishes ds_writes without draining vmcnt (out-stores /
// prefetch loads stay in flight across the barrier). All barrier-protected
// data in this kernel lives in LDS. __syncthreads() would force vmcnt(0).
#define BARRIER() asm volatile("s_waitcnt lgkmcnt(0)\n\ts_barrier" ::: "memory")

__device__ __forceinline__ short f2bf(float f) {
    __hip_bfloat16 h = __float2bfloat16(f);
    return *reinterpret_cast<const short*>(&h);
}

template<int N> struct ic { static constexpr int v = N; };

// ws layout (bytes):
//  w0f bf16[ 98304] @ 0        (layer0 [Wk0;Wr0] 192x512, frag order f=nt*6+kt, nt=w+8g, PRESCALED)
//  w1f bf16[131072] @ 196608   (layer1 [Wk1;Wr1] 256x512, frag order f=nt*8+kt, PRESCALED)
//  wdf bf16[  8192] @ 458752   (Wd 128x64, frag order f=nt*4+kt, unscaled)
//  b0f f32[512]     @ 475136   (PRESCALED)
//  b1f f32[512]     @ 477184   (PRESCALED)
//  bdf f32[64]      @ 479232   (unscaled)
#define W1F_OFF 196608
#define WDF_OFF 458752
#define B0F_OFF 475136
#define B1F_OFF 477184
#define BDF_OFF 479232

__global__ __launch_bounds__(256) void prep_kernel(
    const float* __restrict__ Wk0, const float* __restrict__ Wr0, const float* __restrict__ b0,
    const float* __restrict__ Wk1, const float* __restrict__ Wr1, const float* __restrict__ b1,
    const float* __restrict__ Wd,  const float* __restrict__ bd,  char* __restrict__ ws)
{
    int idx = blockIdx.x * 256 + threadIdx.x;
    short* w0f = (short*)ws;
    short* w1f = (short*)(ws + W1F_OFF);
    short* wdf = (short*)(ws + WDF_OFF);
    float* b0f = (float*)(ws + B0F_OFF);
    float* b1f = (float*)(ws + B1F_OFF);
    float* bdf = (float*)(ws + BDF_OFF);
    const float NL2E = -1.4426950408889634f;   // -log2(e): i,f,o (sigmoid)
    const float N2L2E = -2.8853900817779268f;  // -2log2(e): g (tanh)

    if (idx < 98304) {
        int f = idx >> 9, r = idx & 511;
        int lane = r >> 3, j = r & 7;
        int nt = f / 6, kt = f - nt * 6;
        int k = kt * 32 + (lane >> 4) * 8 + j;
        int col = nt * 16 + (lane & 15);
        float sc = ((col >> 7) == 2) ? N2L2E : NL2E;
        w0f[idx] = f2bf(sc * ((k < Dd) ? Wk0[k * G4 + col] : Wr0[(k - Dd) * G4 + col]));
    } else if (idx < 229376) {
        int i2 = idx - 98304;
        int f = i2 >> 9, r = i2 & 511;
        int lane = r >> 3, j = r & 7;
        int nt = f >> 3, kt = f & 7;
        int k = kt * 32 + (lane >> 4) * 8 + j;
        int col = nt * 16 + (lane & 15);
        float sc = ((col >> 7) == 2) ? N2L2E : NL2E;
        w1f[i2] = f2bf(sc * ((k < 128) ? Wk1[k * G4 + col] : Wr1[(k - 128) * G4 + col]));
    } else if (idx < 237568) {
        int i2 = idx - 229376;
        int f = i2 >> 9, r = i2 & 511;
        int lane = r >> 3, j = r & 7;
        int nt = f >> 2, kt = f & 3;
        int k = kt * 32 + (lane >> 4) * 8 + j;
        int col = nt * 16 + (lane & 15);
        wdf[i2] = f2bf(Wd[k * Dd + col]);
    } else if (idx < 237568 + 1088) {
        int i2 = idx - 237568;
        if (i2 < 512) {
            float sc = ((i2 >> 7) == 2) ? N2L2E : NL2E;
            b0f[i2] = sc * b0[i2];
        } else if (i2 < 1024) {
            int c = i2 - 512;
            float sc = ((c >> 7) == 2) ? N2L2E : NL2E;
            b1f[c] = sc * b1[c];
        } else bdf[i2 - 1024] = bd[i2 - 1024];
    }
}

// Dynamic LDS layout (bytes):
//  a0[2] @ 0     : 2 × 16*72*2  = 4608   (x/pred tiles, ping-pong by step parity)
//  a1[2] @ 4608  : 2 × 16*264*2 = 16896  (h0 | h1 tiles, ping-pong)
//  w0l   @ 21504 : 131072                (W0 pairs p=0..15, [p][wave][512])
//  total 152576 (149 KiB)
#define SM_A1  4608
#define SM_W0  21504
#define SM_TOT 152576
#define A0SZ   1152   // shorts per a0 buffer
#define A1SZ   4224   // shorts per a1 buffer

#define MFMA_B16(A, B, C) __builtin_amdgcn_mfma_f32_16x16x32_bf16((A), (B), (C), 0, 0, 0)

// gate block, fused-rcp form (3 rcp/row instead of 5; algebraically identical):
//   sig(i)*tanh(g) = (1-Eg) / ((1+Ei)(1+Eg)),  E* = 2^(prescaled pre-activation)
//   sig(o)*tanh(c) = (1-Ec) / ((1+Eo)(1+Ec)),  Ec = e^(-2c)
#define GATES(ACC, CS, BASE, COLOFF)                                                     \
    _Pragma("unroll")                                                                    \
    for (int rr = 0; rr < 4; ++rr) {                                                     \
        float Ei = EXP2(ACC[0][rr]);                                                     \
        float Ef = EXP2(ACC[1][rr]);                                                     \
        float Eg = EXP2(ACC[2][rr]);                                                     \
        float Eo = EXP2(ACC[3][rr]);                                                     \
        float ig = (1.0f - Eg) * rcp_((1.0f + Ei) * (1.0f + Eg));                        \
        float c_ = fmaf(rcp_(1.0f + Ef), CS[rr], ig);                                    \
        CS[rr] = c_;                                                                     \
        float Ec = EXP2(c_ * KN2L2E);                                                    \
        float h_ = (1.0f - Ec) * rcp_((1.0f + Eo) * (1.0f + Ec));                        \
        (BASE)[(quad * 4 + rr) * K1P + (COLOFF) + hu] = f2bf(h_);                        \
    }

#define ACC_INIT(ACC, B0_, B1_, B2_, B3_)            \
    ACC[0] = (floatx4){B0_, B0_, B0_, B0_};          \
    ACC[1] = (floatx4){B1_, B1_, B1_, B1_};          \
    ACC[2] = (floatx4){B2_, B2_, B2_, B2_};          \
    ACC[3] = (floatx4){B3_, B3_, B3_, B3_};

// grid 256, block 512 (8 waves), 1 block/CU. Wave w owns hidden cols 16w..16w+15.
// All weights CU-resident. Registers are AT the 256/wave unified cap at this
// occupancy: NO co-live accumulator pairs, NO accumulators carried across the
// dense window or the loop backedge (round-1: -38%, round-3: -11%, both spill).
// Step loop is UNROLLED x2 so the ping-pong parity is compile-time: every LDS
// access folds to base_vreg + offset-immediate instead of per-step v_add
// address chains (the theory for round-2's 42% VALUBusy). Schedule per step is
// identical to the 402us round-2 kernel: 1 barrier/warm step, 3/AR step,
// LDS-only (lgkmcnt) barriers.
__global__ __launch_bounds__(512, 2) void lstm_kernel(
    const float* __restrict__ x, const char* __restrict__ ws, float* __restrict__ out)
{
    extern __shared__ char smem[];
    short* a0b = (short*)smem;                 // 2 buffers of A0SZ
    short* a1b = (short*)(smem + SM_A1);       // 2 buffers of A1SZ
    short* w0l = (short*)(smem + SM_W0);

    const short* w0f = (const short*)ws;
    const short* w1f = (const short*)(ws + W1F_OFF);
    const short* wdf = (const short*)(ws + WDF_OFF);
    const float* b0f = (const float*)(ws + B0F_OFF);
    const float* b1f = (const float*)(ws + B1F_OFF);
    const float* bdf = (const float*)(ws + BDF_OFF);

    const int tid  = threadIdx.x;
    const int w    = tid >> 6;        // wave 0..7
    const int lane = tid & 63;
    const int l15  = lane & 15;
    const int quad = lane >> 4;
    const int row0 = blockIdx.x * BM;

    // ---- one-time staging ----
    for (int i = tid; i < 2 * A0SZ; i += 512) a0b[i] = 0;
    for (int i = tid; i < 2 * A1SZ; i += 512) a1b[i] = 0;
    // W0 pairs p<16 -> LDS
    for (int c = tid; c < 8192; c += 512) {       // short8 chunks
        int e8 = c & 63;
        int wv = (c >> 6) & 7;
        int p  = c >> 9;                           // 0..15
        int g = p / 6, kt = p - g * 6;
        const short* src = w0f + ((((g * 8 + wv) * 6) + kt) << 9) + e8 * 8;
        *(short8*)&w0l[((p * 8 + wv) << 9) + e8 * 8] = *(const short8*)src;
    }
    {   // stage x_0 -> a0[0]
        int cx = tid & 63, rg2 = tid >> 6;
        a0b[rg2 * K0S + cx]       = f2bf(x[(size_t)(row0 + rg2) * (Tt * Dd) + cx]);
        a0b[(rg2 + 8) * K0S + cx] = f2bf(x[(size_t)(row0 + rg2 + 8) * (Tt * Dd) + cx]);
    }

    // register-resident weights
    const short* w0rb = w0f + w * 3072 + lane * 8;
    const short* w1rb = w1f + w * 4096 + lane * 8;
    short8 W1R[4][8];
    #pragma unroll
    for (int g = 0; g < 4; ++g)
        #pragma unroll
        for (int kt = 0; kt < 8; ++kt)
            W1R[g][kt] = *(const short8*)(w1rb + g * 32768 + kt * 512);
    short8 W0R[8];   // pairs p = 16..23
    #pragma unroll
    for (int p = 16; p < 24; ++p) {
        int g = p / 6, kt = p - g * 6;
        W0R[p - 16] = *(const short8*)(w0rb + g * 24576 + kt * 512);
    }
    short8 WdR[4];
    if (w < 4) {
        #pragma unroll
        for (int kt = 0; kt < 4; ++kt)
            WdR[kt] = *(const short8*)(wdf + ((w * 4 + kt) << 9) + lane * 8);
    }

    const int hu = w * 16 + l15;
    const float bi0 = b0f[hu], bff0 = b0f[128 + hu], bg0 = b0f[256 + hu], bo0 = b0f[384 + hu];
    const float bi1 = b1f[hu], bff1 = b1f[128 + hu], bg1 = b1f[256 + hu], bo1 = b1f[384 + hu];
    const float bdv = bdf[(w & 3) * 16 + l15];

    float c0s[4] = {0.f, 0.f, 0.f, 0.f};
    float c1s[4] = {0.f, 0.f, 0.f, 0.f};

    const int colx = tid & 63, rg = tid >> 6;

    __syncthreads();   // staging complete (one full sync is fine here)

    // One step. P (buffer parity), TAIL (dense head), STAGE (x prefetch) are
    // compile-time -> all LDS addresses are base + constant-offset.
    auto body = [&](auto PC, auto TC, auto SC, int step) {
        constexpr int  P     = decltype(PC)::v;
        constexpr bool TAIL  = decltype(TC)::v != 0;
        constexpr bool STAGE = decltype(SC)::v != 0;

        short* a0p = a0b + P * A0SZ;        short* a0q = a0b + (P ^ 1) * A0SZ;
        short* a1p = a1b + P * A1SZ;        short* a1q = a1b + (P ^ 1) * A1SZ;

        // issue next-x global loads early (consumed at step bottom)
        float xv0, xv1;
        if constexpr (STAGE) {
            xv0 = x[(size_t)(row0 + rg)     * (Tt * Dd) + (step + 1) * Dd + colx];
            xv1 = x[(size_t)(row0 + rg + 8) * (Tt * Dd) + (step + 1) * Dd + colx];
        }

        // ---------- layer 0: A = [x|h0], x from a0[P], h0 from a1[P^1] ----------
        floatx4 acc[4];
        ACC_INIT(acc, bi0, bff0, bg0, bo0);
        #pragma unroll
        for (int kt = 0; kt < 6; ++kt) {
            short8 af = (kt < 2)
                ? *(const short8*)&a0p[l15 * K0S + kt * 32 + quad * 8]
                : *(const short8*)&a1q[l15 * K1P + (kt - 2) * 32 + quad * 8];
            #pragma unroll
            for (int g = 0; g < 4; ++g) {
                const int pp = g * 6 + kt;
                short8 bfr = (pp < 16) ? *(const short8*)&w0l[((pp * 8 + w) << 9) + lane * 8]
                                       : W0R[pp - 16];
                acc[g] = MFMA_B16(af, bfr, acc[g]);
            }
        }

        // ---------- gates layer 0 -> h0' into a1[P] cols 0..127 ----------
        GATES(acc, c0s, a1p, 0);

        // stage next x into a0[P^1] (before the barrier that publishes it)
        if constexpr (STAGE) {
            a0q[rg * K0S + colx]       = f2bf(xv0);
            a0q[(rg + 8) * K0S + colx] = f2bf(xv1);
        }
        BARRIER();   // C: h0' (and next-x) visible

        // ---------- layer 1: A = a1[P] (h0' | h1) ----------
        ACC_INIT(acc, bi1, bff1, bg1, bo1);
        #pragma unroll
        for (int kt = 0; kt < 8; ++kt) {
            short8 af = *(const short8*)&a1p[l15 * K1P + kt * 32 + quad * 8];
            #pragma unroll
            for (int g = 0; g < 4; ++g)
                acc[g] = MFMA_B16(af, W1R[g][kt], acc[g]);
        }

        // ---------- gates layer 1 -> h1' into a1[P^1] cols 128..255 ----------
        GATES(acc, c1s, a1q, 128);

        // ---------- dense head: pred = h1' @ Wd + bd ----------
        if constexpr (TAIL) {
            BARRIER();   // D: h1' visible
            if (w < 4) {
                floatx4 ad = (floatx4){bdv, bdv, bdv, bdv};
                #pragma unroll
                for (int kt = 0; kt < 4; ++kt) {
                    short8 a_ = *(const short8*)&a1q[l15 * K1P + 128 + kt * 32 + quad * 8];
                    ad = MFMA_B16(a_, WdR[kt], ad);
                }
                int s = step - (Tt - 1);
                #pragma unroll
                for (int r = 0; r < 4; ++r) {
                    float pv = ad[r];
                    int row = quad * 4 + r;
                    int col = w * 16 + l15;
                    out[(size_t)(row0 + row) * (NOUT * Dd) + s * Dd + col] = pv;
                    a0q[row * K0S + col] = f2bf(pv);   // AR feedback for step+1
                }
            }
            BARRIER();   // E: publish pred before next step's L0 reads a0[P^1]
        }
    };

    // steps 0..47: warm, unrolled x2 (compile-time parity)
    #pragma unroll 1
    for (int it = 0; it < 24; ++it) {
        body(ic<0>{}, ic<0>{}, ic<1>{}, 2 * it);
        body(ic<1>{}, ic<0>{}, ic<1>{}, 2 * it + 1);
    }
    // step 48: last warm step (stages x(49))
    body(ic<0>{}, ic<0>{}, ic<1>{}, 48);
    // steps 49..148: AR, unrolled x2 (parities 1,0)
    #pragma unroll 1
    for (int it = 0; it < 50; ++it) {
        body(ic<1>{}, ic<1>{}, ic<0>{}, 49 + 2 * it);
        body(ic<0>{}, ic<1>{}, ic<0>{}, 50 + 2 * it);
    }
}

extern "C" void kernel_launch(void* const* d_in, const int* in_sizes, int n_in,
                              void* d_out, int out_size, void* d_ws, size_t ws_size,
                              hipStream_t stream)
{
    (void)in_sizes; (void)n_in; (void)out_size; (void)ws_size;
    static_assert(SM_TOT <= 160 * 1024, "LDS budget");
    hipFuncSetAttribute(reinterpret_cast<const void*>(lstm_kernel),
                        hipFuncAttributeMaxDynamicSharedMemorySize, SM_TOT);
    prep_kernel<<<933, 256, 0, stream>>>(
        (const float*)d_in[1], (const float*)d_in[2], (const float*)d_in[3],
        (const float*)d_in[4], (const float*)d_in[5], (const float*)d_in[6],
        (const float*)d_in[7], (const float*)d_in[8], (char*)d_ws);
    lstm_kernel<<<256, 512, SM_TOT, stream>>>(
        (const float*)d_in[0], (const char*)d_ws, (float*)d_out);
}

// Round 5
// 468.629 us; speedup vs baseline: 1.2107x; 1.2107x over previous
//
#include <hip/hip_runtime.h>
#include <hip/hip_bf16.h>

// Problem constants
#define Tt   50
#define Dd   64
#define NOUT 100
#define G4   512   // 4*H
#define K0S  72    // a0 LDS stride (64 x-cols + 8 pad)
#define K1P  264   // a1 LDS stride (256 + 8 pad)
#define BM   16    // batch rows per workgroup (grid 256 = 4096/16)

typedef __attribute__((ext_vector_type(8))) short  short8;
typedef __attribute__((ext_vector_type(4))) float  floatx4;

#if __has_builtin(__builtin_amdgcn_exp2f)
#define EXP2(v) __builtin_amdgcn_exp2f(v)
#else
#define EXP2(v) exp2f(v)
#endif
__device__ __forceinline__ float rcp_(float v) { return __builtin_amdgcn_rcpf(v); }
#define KN2L2E (-2.8853900817779268f)   // -2*log2(e), for tanh(c) with natural-units c

// LDS-only barrier: publishes ds_writes without draining vmcnt (out-stores /
// prefetch loads stay in flight across the barrier). All barrier-protected
// data in this kernel lives in LDS. __syncthreads() would force vmcnt(0).
#define BARRIER() asm volatile("s_waitcnt lgkmcnt(0)\n\ts_barrier" ::: "memory")

__device__ __forceinline__ short f2bf(float f) {
    __hip_bfloat16 h = __float2bfloat16(f);
    return *reinterpret_cast<const short*>(&h);
}

// ws layout (bytes):
//  w0f bf16[ 98304] @ 0        (layer0 [Wk0;Wr0] 192x512, frag order f=nt*6+kt, nt=w+8g, PRESCALED)
//  w1f bf16[131072] @ 196608   (layer1 [Wk1;Wr1] 256x512, frag order f=nt*8+kt, PRESCALED)
//  wdf bf16[  8192] @ 458752   (Wd 128x64, frag order f=nt*4+kt, unscaled)
//  b0f f32[512]     @ 475136   (PRESCALED)
//  b1f f32[512]     @ 477184   (PRESCALED)
//  bdf f32[64]      @ 479232   (unscaled)
#define W1F_OFF 196608
#define WDF_OFF 458752
#define B0F_OFF 475136
#define B1F_OFF 477184
#define BDF_OFF 479232

__global__ __launch_bounds__(256) void prep_kernel(
    const float* __restrict__ Wk0, const float* __restrict__ Wr0, const float* __restrict__ b0,
    const float* __restrict__ Wk1, const float* __restrict__ Wr1, const float* __restrict__ b1,
    const float* __restrict__ Wd,  const float* __restrict__ bd,  char* __restrict__ ws)
{
    int idx = blockIdx.x * 256 + threadIdx.x;
    short* w0f = (short*)ws;
    short* w1f = (short*)(ws + W1F_OFF);
    short* wdf = (short*)(ws + WDF_OFF);
    float* b0f = (float*)(ws + B0F_OFF);
    float* b1f = (float*)(ws + B1F_OFF);
    float* bdf = (float*)(ws + BDF_OFF);
    const float NL2E = -1.4426950408889634f;   // -log2(e): i,f,o (sigmoid)
    const float N2L2E = -2.8853900817779268f;  // -2log2(e): g (tanh)

    if (idx < 98304) {
        int f = idx >> 9, r = idx & 511;
        int lane = r >> 3, j = r & 7;
        int nt = f / 6, kt = f - nt * 6;
        int k = kt * 32 + (lane >> 4) * 8 + j;
        int col = nt * 16 + (lane & 15);
        float sc = ((col >> 7) == 2) ? N2L2E : NL2E;
        w0f[idx] = f2bf(sc * ((k < Dd) ? Wk0[k * G4 + col] : Wr0[(k - Dd) * G4 + col]));
    } else if (idx < 229376) {
        int i2 = idx - 98304;
        int f = i2 >> 9, r = i2 & 511;
        int lane = r >> 3, j = r & 7;
        int nt = f >> 3, kt = f & 7;
        int k = kt * 32 + (lane >> 4) * 8 + j;
        int col = nt * 16 + (lane & 15);
        float sc = ((col >> 7) == 2) ? N2L2E : NL2E;
        w1f[i2] = f2bf(sc * ((k < 128) ? Wk1[k * G4 + col] : Wr1[(k - 128) * G4 + col]));
    } else if (idx < 237568) {
        int i2 = idx - 229376;
        int f = i2 >> 9, r = i2 & 511;
        int lane = r >> 3, j = r & 7;
        int nt = f >> 2, kt = f & 3;
        int k = kt * 32 + (lane >> 4) * 8 + j;
        int col = nt * 16 + (lane & 15);
        wdf[i2] = f2bf(Wd[k * Dd + col]);
    } else if (idx < 237568 + 1088) {
        int i2 = idx - 237568;
        if (i2 < 512) {
            float sc = ((i2 >> 7) == 2) ? N2L2E : NL2E;
            b0f[i2] = sc * b0[i2];
        } else if (i2 < 1024) {
            int c = i2 - 512;
            float sc = ((c >> 7) == 2) ? N2L2E : NL2E;
            b1f[c] = sc * b1[c];
        } else bdf[i2 - 1024] = bd[i2 - 1024];
    }
}

// Dynamic LDS layout (bytes):
//  a0[2] @ 0     : 2 × 16*72*2  = 4608   (x/pred tiles, ping-pong by step parity)
//  a1[2] @ 4608  : 2 × 16*264*2 = 16896  (h0 | h1 tiles, ping-pong)
//  w0l   @ 21504 : 131072                (W0 pairs p=0..15, [p][wave][512])
//  total 152576 (149 KiB)
#define SM_A1  4608
#define SM_W0  21504
#define SM_TOT 152576
#define A0SZ   1152   // shorts per a0 buffer
#define A1SZ   4224   // shorts per a1 buffer

#define MFMA_B16(A, B, C) __builtin_amdgcn_mfma_f32_16x16x32_bf16((A), (B), (C), 0, 0, 0)

// gate block, fused-rcp form (3 rcp/row instead of 5; algebraically identical):
//   sig(i)*tanh(g) = (1-Eg) / ((1+Ei)(1+Eg)),  E* = 2^(prescaled pre-activation)
//   sig(o)*tanh(c) = (1-Ec) / ((1+Eo)(1+Ec)),  Ec = e^(-2c)
#define GATES(ACC, CS, BASE, COLOFF)                                                     \
    _Pragma("unroll")                                                                    \
    for (int rr = 0; rr < 4; ++rr) {                                                     \
        float Ei = EXP2(ACC[0][rr]);                                                     \
        float Ef = EXP2(ACC[1][rr]);                                                     \
        float Eg = EXP2(ACC[2][rr]);                                                     \
        float Eo = EXP2(ACC[3][rr]);                                                     \
        float ig = (1.0f - Eg) * rcp_((1.0f + Ei) * (1.0f + Eg));                        \
        float c_ = fmaf(rcp_(1.0f + Ef), CS[rr], ig);                                    \
        CS[rr] = c_;                                                                     \
        float Ec = EXP2(c_ * KN2L2E);                                                    \
        float h_ = (1.0f - Ec) * rcp_((1.0f + Eo) * (1.0f + Ec));                        \
        (BASE)[(quad * 4 + rr) * K1P + (COLOFF) + hu] = f2bf(h_);                        \
    }

#define ACC_INIT(ACC, B0_, B1_, B2_, B3_)            \
    ACC[0] = (floatx4){B0_, B0_, B0_, B0_};          \
    ACC[1] = (floatx4){B1_, B1_, B1_, B1_};          \
    ACC[2] = (floatx4){B2_, B2_, B2_, B2_};          \
    ACC[3] = (floatx4){B3_, B3_, B3_, B3_};

// one L0 k-tile: kt<2 = x-part (a0p), kt>=2 = h0-part (a1q)
#define L0KT(KT)                                                                          \
    {                                                                                     \
        short8 af = ((KT) < 2)                                                            \
            ? *(const short8*)&a0p[l15 * K0S + (KT) * 32 + quad * 8]                      \
            : *(const short8*)&a1q[l15 * K1P + ((KT) - 2) * 32 + quad * 8];               \
        _Pragma("unroll")                                                                 \
        for (int g = 0; g < 4; ++g) {                                                     \
            const int pp = g * 6 + (KT);                                                  \
            short8 bfr = (pp < 16) ? *(const short8*)&w0l[((pp * 8 + w) << 9) + lane * 8] \
                                   : W0R[pp - 16];                                        \
            acc[g] = MFMA_B16(af, bfr, acc[g]);                                           \
        }                                                                                 \
    }

// grid 256, block 512 (8 waves), 1 block/CU. Wave w owns hidden cols 16w..16w+15.
// All weights CU-resident. REGISTER DISCIPLINE (hard-won): the 256-reg/wave
// unified budget is EXACTLY full. Round-1 (co-live acc pair), round-3 (acc
// carried across dense barriers), round-4 (x2 unroll stretching live ranges)
// all spilled to scratch and regressed 10-38%. Do not extend any live range
// across a barrier or step boundary. Schedule: 1 barrier/warm step, 3/AR step,
// LDS-only (lgkmcnt) barriers. This round: setprio(1) around MFMA bursts
// (issue arbitration vs SIMD-mate gate TRANS), dense ad-chain split 4->2+2,
// feedback LDS writes before global stores, AR-friendly kt order (h-part
// first, freshest pred-dependent x-part last).
__global__ __launch_bounds__(512, 2) void lstm_kernel(
    const float* __restrict__ x, const char* __restrict__ ws, float* __restrict__ out)
{
    extern __shared__ char smem[];
    short* a0b = (short*)smem;                 // 2 buffers of A0SZ
    short* a1b = (short*)(smem + SM_A1);       // 2 buffers of A1SZ
    short* w0l = (short*)(smem + SM_W0);

    const short* w0f = (const short*)ws;
    const short* w1f = (const short*)(ws + W1F_OFF);
    const short* wdf = (const short*)(ws + WDF_OFF);
    const float* b0f = (const float*)(ws + B0F_OFF);
    const float* b1f = (const float*)(ws + B1F_OFF);
    const float* bdf = (const float*)(ws + BDF_OFF);

    const int tid  = threadIdx.x;
    const int w    = tid >> 6;        // wave 0..7
    const int lane = tid & 63;
    const int l15  = lane & 15;
    const int quad = lane >> 4;
    const int row0 = blockIdx.x * BM;

    // ---- one-time staging ----
    for (int i = tid; i < 2 * A0SZ; i += 512) a0b[i] = 0;
    for (int i = tid; i < 2 * A1SZ; i += 512) a1b[i] = 0;
    // W0 pairs p<16 -> LDS
    for (int c = tid; c < 8192; c += 512) {       // short8 chunks
        int e8 = c & 63;
        int wv = (c >> 6) & 7;
        int p  = c >> 9;                           // 0..15
        int g = p / 6, kt = p - g * 6;
        const short* src = w0f + ((((g * 8 + wv) * 6) + kt) << 9) + e8 * 8;
        *(short8*)&w0l[((p * 8 + wv) << 9) + e8 * 8] = *(const short8*)src;
    }
    {   // stage x_0 -> a0[0]
        int cx = tid & 63, rg2 = tid >> 6;
        a0b[rg2 * K0S + cx]       = f2bf(x[(size_t)(row0 + rg2) * (Tt * Dd) + cx]);
        a0b[(rg2 + 8) * K0S + cx] = f2bf(x[(size_t)(row0 + rg2 + 8) * (Tt * Dd) + cx]);
    }

    // register-resident weights
    const short* w0rb = w0f + w * 3072 + lane * 8;
    const short* w1rb = w1f + w * 4096 + lane * 8;
    short8 W1R[4][8];
    #pragma unroll
    for (int g = 0; g < 4; ++g)
        #pragma unroll
        for (int kt = 0; kt < 8; ++kt)
            W1R[g][kt] = *(const short8*)(w1rb + g * 32768 + kt * 512);
    short8 W0R[8];   // pairs p = 16..23
    #pragma unroll
    for (int p = 16; p < 24; ++p) {
        int g = p / 6, kt = p - g * 6;
        W0R[p - 16] = *(const short8*)(w0rb + g * 24576 + kt * 512);
    }
    short8 WdR[4];
    if (w < 4) {
        #pragma unroll
        for (int kt = 0; kt < 4; ++kt)
            WdR[kt] = *(const short8*)(wdf + ((w * 4 + kt) << 9) + lane * 8);
    }

    const int hu = w * 16 + l15;
    const float bi0 = b0f[hu], bff0 = b0f[128 + hu], bg0 = b0f[256 + hu], bo0 = b0f[384 + hu];
    const float bi1 = b1f[hu], bff1 = b1f[128 + hu], bg1 = b1f[256 + hu], bo1 = b1f[384 + hu];
    const float bdv = bdf[(w & 3) * 16 + l15];

    float c0s[4] = {0.f, 0.f, 0.f, 0.f};
    float c1s[4] = {0.f, 0.f, 0.f, 0.f};

    const int colx = tid & 63, rg = tid >> 6;

    __syncthreads();   // staging complete (one full sync is fine here)

    for (int step = 0; step < 149; ++step) {
        const int p = step & 1, q = p ^ 1;
        short* a0p = a0b + p * A0SZ;  short* a0q = a0b + q * A0SZ;
        short* a1p = a1b + p * A1SZ;  short* a1q = a1b + q * A1SZ;

        // issue next-x global loads early (consumed at step bottom)
        float xv0, xv1;
        if (step < Tt - 1) {
            xv0 = x[(size_t)(row0 + rg)     * (Tt * Dd) + (step + 1) * Dd + colx];
            xv1 = x[(size_t)(row0 + rg + 8) * (Tt * Dd) + (step + 1) * Dd + colx];
        }

        // ---------- layer 0: A = [x|h0], x from a0[p], h0 from a1[q] ----------
        // h-part (kt 2..5, data from prev barrier C) first; x-part (kt 0..1,
        // pred published at the most recent barrier E in AR) last.
        floatx4 acc[4];
        ACC_INIT(acc, bi0, bff0, bg0, bo0);
        __builtin_amdgcn_s_setprio(1);
        L0KT(2) L0KT(3) L0KT(4) L0KT(5) L0KT(0) L0KT(1)
        __builtin_amdgcn_s_setprio(0);

        // ---------- gates layer 0 -> h0' into a1[p] cols 0..127 ----------
        GATES(acc, c0s, a1p, 0);

        // stage next x into a0[q] (before the barrier that publishes it)
        if (step < Tt - 1) {
            a0q[rg * K0S + colx]       = f2bf(xv0);
            a0q[(rg + 8) * K0S + colx] = f2bf(xv1);
        }
        BARRIER();   // C: h0' (and next-x) visible

        // ---------- layer 1: A = a1[p] (h0' | h1) ----------
        ACC_INIT(acc, bi1, bff1, bg1, bo1);
        __builtin_amdgcn_s_setprio(1);
        #pragma unroll
        for (int kt = 0; kt < 8; ++kt) {
            short8 af = *(const short8*)&a1p[l15 * K1P + kt * 32 + quad * 8];
            #pragma unroll
            for (int g = 0; g < 4; ++g)
                acc[g] = MFMA_B16(af, W1R[g][kt], acc[g]);
        }
        __builtin_amdgcn_s_setprio(0);

        // ---------- gates layer 1 -> h1' into a1[q] cols 128..255 ----------
        GATES(acc, c1s, a1q, 128);

        // ---------- dense head (steps >= 49): pred = h1' @ Wd + bd ----------
        if (step >= Tt - 1) {
            BARRIER();   // D: h1' visible
            if (w < 4) {
                // two independent 2-deep MFMA chains (halves serial latency
                // in the D->E window), summed at the end
                floatx4 ad0 = (floatx4){bdv, bdv, bdv, bdv};
                floatx4 ad1 = (floatx4){0.f, 0.f, 0.f, 0.f};
                __builtin_amdgcn_s_setprio(1);
                {
                    short8 a0_ = *(const short8*)&a1q[l15 * K1P + 128 +  0 + quad * 8];
                    short8 a1_ = *(const short8*)&a1q[l15 * K1P + 128 + 32 + quad * 8];
                    short8 a2_ = *(const short8*)&a1q[l15 * K1P + 128 + 64 + quad * 8];
                    short8 a3_ = *(const short8*)&a1q[l15 * K1P + 128 + 96 + quad * 8];
                    ad0 = MFMA_B16(a0_, WdR[0], ad0);
                    ad1 = MFMA_B16(a1_, WdR[1], ad1);
                    ad0 = MFMA_B16(a2_, WdR[2], ad0);
                    ad1 = MFMA_B16(a3_, WdR[3], ad1);
                }
                __builtin_amdgcn_s_setprio(0);
                float pv0 = ad0[0] + ad1[0], pv1 = ad0[1] + ad1[1];
                float pv2 = ad0[2] + ad1[2], pv3 = ad0[3] + ad1[3];
                int col = w * 16 + l15;
                // LDS feedback first (barrier E waits only on these) ...
                a0q[(quad * 4 + 0) * K0S + col] = f2bf(pv0);
                a0q[(quad * 4 + 1) * K0S + col] = f2bf(pv1);
                a0q[(quad * 4 + 2) * K0S + col] = f2bf(pv2);
                a0q[(quad * 4 + 3) * K0S + col] = f2bf(pv3);
                // ... then fire-and-forget global stores (not tracked by lgkmcnt)
                int s = step - (Tt - 1);
                size_t ob = (size_t)(row0 + quad * 4) * (NOUT * Dd) + s * Dd + col;
                out[ob]                 = pv0;
                out[ob + 1 * NOUT * Dd] = pv1;
                out[ob + 2 * NOUT * Dd] = pv2;
                out[ob + 3 * NOUT * Dd] = pv3;
            }
            BARRIER();   // E: publish pred before next step's L0 reads a0[q]
        }
    }
}

extern "C" void kernel_launch(void* const* d_in, const int* in_sizes, int n_in,
                              void* d_out, int out_size, void* d_ws, size_t ws_size,
                              hipStream_t stream)
{
    (void)in_sizes; (void)n_in; (void)out_size; (void)ws_size;
    static_assert(SM_TOT <= 160 * 1024, "LDS budget");
    hipFuncSetAttribute(reinterpret_cast<const void*>(lstm_kernel),
                        hipFuncAttributeMaxDynamicSharedMemorySize, SM_TOT);
    prep_kernel<<<933, 256, 0, stream>>>(
        (const float*)d_in[1], (const float*)d_in[2], (const float*)d_in[3],
        (const float*)d_in[4], (const float*)d_in[5], (const float*)d_in[6],
        (const float*)d_in[7], (const float*)d_in[8], (char*)d_ws);
    lstm_kernel<<<256, 512, SM_TOT, stream>>>(
        (const float*)d_in[0], (const char*)d_ws, (float*)d_out);
}